// Round 5
// baseline (736.314 us; speedup 1.0000x reference)
//
#include <hip/hip_runtime.h>
#include <float.h>

#define NEG_SLOPE 0.2f

__device__ __forceinline__ float lrelu(float x) { return x >= 0.0f ? x : NEG_SLOPE * x; }

// ============ prep: transpose conv weights ============
// wat[c*256 + r*64 + kx*16 + co] = wa[co*(CIN*16) + c*16 + r*4 + kx]
// wbt[k*16 + co]                 = wb[co*16 + k]
struct PrepSeg { const float* wa; const float* wb; float* wat; float* wbt; int CIN; };
struct PrepTab { PrepSeg seg[5]; };

__global__ __launch_bounds__(256)
void prep_weights(PrepTab tab) {
    PrepSeg sg = tab.seg[blockIdx.x];
    int n = sg.CIN * 256;
    for (int i = threadIdx.x; i < n; i += 256)
        sg.wat[i] = sg.wa[(i & 15) * (sg.CIN * 16) + (i >> 4)];
    sg.wbt[threadIdx.x] = sg.wb[(threadIdx.x & 15) * 16 + (threadIdx.x >> 4)];
}

// ============ über tile-conv ============
// left (SX=4): 1 output/thread, aligned float4 loads (col 4x, 16B-aligned).
// right (SX=1): 4 outputs/thread at 4-aligned column base; two ALIGNED float4 loads
//               per (c,row) cover all 4 sliding windows; f1=0 handles the W-pad tail.
struct ConvSeg {
    const float* in; const float* wat; const float* wbt; const float* ba; const float* bb;
    float* out;
    int CIN, H, W, right, nit, npix, blk0;
};
struct ConvTab { ConvSeg seg[10]; };

__global__ __launch_bounds__(256)
void conv_uber(ConvTab tab) {
    int si = 0;
#pragma unroll
    for (int i = 1; i < 10; i++) if ((int)blockIdx.x >= tab.seg[i].blk0) si = i;
    const ConvSeg sg = tab.seg[si];

    int t = ((int)blockIdx.x - sg.blk0) * 256 + threadIdx.x;
    const bool valid = t < sg.nit;
    int ct = valid ? t : sg.nit - 1;
    const int W = sg.W, H = sg.H, CIN = sg.CIN;
    const int W4 = W >> 2;
    int y = ct / W4, xq = ct - y * W4;
    int colb = 4 * xq;
    const float* ib = sg.in + (size_t)(4 * y) * W + colb;

    if (sg.right) {
        float m[4][16];
#pragma unroll
        for (int i = 0; i < 4; i++)
#pragma unroll
            for (int co = 0; co < 16; co++) m[i][co] = 0.f;

        const bool has1 = colb + 4 < W;
        for (int c = 0; c < CIN; c++) {
            const float* rb = ib + (size_t)c * H * W;
            const float* wc = sg.wat + c * 256;
#pragma unroll
            for (int r = 0; r < 4; r++) {
                float4 f0 = *(const float4*)(rb + r * W);
                float4 f1 = make_float4(0.f, 0.f, 0.f, 0.f);
                if (has1) f1 = *(const float4*)(rb + r * W + 4);
                float wv[8] = {f0.x, f0.y, f0.z, f0.w, f1.x, f1.y, f1.z, f1.w};
                const float* wr = wc + r * 64;
#pragma unroll
                for (int i = 0; i < 4; i++) {
#pragma unroll
                    for (int kx = 0; kx < 4; kx++) {
                        float v = wv[i + kx];
                        const float* w2 = wr + kx * 16;
#pragma unroll
                        for (int co = 0; co < 16; co++) m[i][co] = fmaf(v, w2[co], m[i][co]);
                    }
                }
            }
        }
        // epilogue: bias+lrelu, 1x1 conv, packed float4 store per co
        float o[4][16];
#pragma unroll
        for (int i = 0; i < 4; i++) {
#pragma unroll
            for (int co = 0; co < 16; co++) m[i][co] = lrelu(m[i][co] + sg.ba[co]);
#pragma unroll
            for (int co = 0; co < 16; co++) o[i][co] = 0.f;
#pragma unroll
            for (int k = 0; k < 16; k++) {
                float mk = m[i][k];
                const float* wr = sg.wbt + k * 16;
#pragma unroll
                for (int co = 0; co < 16; co++) o[i][co] = fmaf(mk, wr[co], o[i][co]);
            }
        }
        if (valid) {
            size_t base = (size_t)y * W + colb;
#pragma unroll
            for (int co = 0; co < 16; co++) {
                float4 v = make_float4(lrelu(o[0][co] + sg.bb[co]), lrelu(o[1][co] + sg.bb[co]),
                                       lrelu(o[2][co] + sg.bb[co]), lrelu(o[3][co] + sg.bb[co]));
                *(float4*)(sg.out + (size_t)co * sg.npix + base) = v;
            }
        }
    } else {
        float m[16];
#pragma unroll
        for (int co = 0; co < 16; co++) m[co] = 0.f;
        for (int c = 0; c < CIN; c++) {
            const float* rb = ib + (size_t)c * H * W;
            const float* wc = sg.wat + c * 256;
#pragma unroll
            for (int r = 0; r < 4; r++) {
                float4 v = *(const float4*)(rb + r * W);
                const float* wr = wc + r * 64;
#pragma unroll
                for (int co = 0; co < 16; co++) m[co] = fmaf(v.x, wr[co], m[co]);
#pragma unroll
                for (int co = 0; co < 16; co++) m[co] = fmaf(v.y, wr[16 + co], m[co]);
#pragma unroll
                for (int co = 0; co < 16; co++) m[co] = fmaf(v.z, wr[32 + co], m[co]);
#pragma unroll
                for (int co = 0; co < 16; co++) m[co] = fmaf(v.w, wr[48 + co], m[co]);
            }
        }
#pragma unroll
        for (int co = 0; co < 16; co++) m[co] = lrelu(m[co] + sg.ba[co]);
        float o[16];
#pragma unroll
        for (int co = 0; co < 16; co++) o[co] = 0.f;
#pragma unroll
        for (int k = 0; k < 16; k++) {
            float mk = m[k];
            const float* wr = sg.wbt + k * 16;
#pragma unroll
            for (int co = 0; co < 16; co++) o[co] = fmaf(mk, wr[co], o[co]);
        }
        if (valid) {
#pragma unroll
            for (int co = 0; co < 16; co++)
                sg.out[(size_t)co * sg.nit + t] = lrelu(o[co] + sg.bb[co]);
        }
    }
}

// ============ über cost-volume + argmin + hyp head (unchanged) ============
struct CvSeg {
    const float* tl; const float* tr; const float* feat;
    const float* dw; const float* db;
    float* cv; float* hyp;
    int h, w4, w, D, gpc, CF, blk0;
};
struct CvTab { CvSeg seg[5]; };

__global__ __launch_bounds__(256)
void cv_hyp_uber(CvTab tab) {
    __shared__ float smin[256];
    __shared__ int sarg[256];

    int si = 0;
#pragma unroll
    for (int i = 1; i < 5; i++) if ((int)blockIdx.x >= tab.seg[i].blk0) si = i;
    const CvSeg sg = tab.seg[si];

    const int npix = sg.h * sg.w4;
    const int p = threadIdx.x & 63, chunk = threadIdx.x >> 6;
    const int pix = ((int)blockIdx.x - sg.blk0) * 64 + p;
    const bool valid = pix < npix;

    float mloc = FLT_MAX; int aloc = 0;
    if (valid) {
        int y = pix / sg.w4, j = pix - y * sg.w4;
        float tlv[16]; float sumabs = 0.f;
#pragma unroll
        for (int c = 0; c < 16; c++) { tlv[c] = sg.tl[(size_t)c * npix + pix]; sumabs += fabsf(tlv[c]); }

        int ngroups = sg.D >> 2;
        int g0 = chunk * sg.gpc;
        int g1 = min(ngroups, g0 + sg.gpc);
        const float* trrow = sg.tr + (size_t)y * sg.w;
        int hw = sg.h * sg.w;

        float carry[16];
        int b0 = 4 * j - 4 * g0;
        if (g0 < g1 && b0 >= 0) {
#pragma unroll
            for (int c = 0; c < 16; c++) carry[c] = trrow[(size_t)c * hw + b0];
        }
        for (int g = g0; g < g1; g++) {
            int b = 4 * j - 4 * g;
            float a0, a1, a2, a3;
            if (b >= 4) {
                a0 = a1 = a2 = a3 = 0.f;
#pragma unroll
                for (int c = 0; c < 16; c++) {
                    float4 f0 = *(const float4*)(trrow + (size_t)c * hw + (b - 4));
                    float tv = tlv[c];
                    a0 += fabsf(tv - carry[c]);
                    a1 += fabsf(tv - f0.w);
                    a2 += fabsf(tv - f0.z);
                    a3 += fabsf(tv - f0.y);
                    carry[c] = f0.x;
                }
            } else if (b == 0) {
                a0 = 0.f; a1 = a2 = a3 = sumabs;
#pragma unroll
                for (int c = 0; c < 16; c++) a0 += fabsf(tlv[c] - carry[c]);
            } else {
                a0 = a1 = a2 = a3 = sumabs;
            }
            float* cvp = sg.cv + (size_t)(4 * g) * npix + pix;
            cvp[0] = a0; cvp[npix] = a1; cvp[2 * (size_t)npix] = a2; cvp[3 * (size_t)npix] = a3;
            if (a0 < mloc) { mloc = a0; aloc = 4 * g; }
            if (a1 < mloc) { mloc = a1; aloc = 4 * g + 1; }
            if (a2 < mloc) { mloc = a2; aloc = 4 * g + 2; }
            if (a3 < mloc) { mloc = a3; aloc = 4 * g + 3; }
        }
    }
    smin[threadIdx.x] = mloc;
    sarg[threadIdx.x] = aloc;
    __syncthreads();

    if (threadIdx.x < 64 && valid) {
        float mn = smin[threadIdx.x]; int arg = sarg[threadIdx.x];
#pragma unroll
        for (int c2 = 1; c2 < 4; c2++) {
            float v = smin[c2 * 64 + threadIdx.x];
            if (v < mn) { mn = v; arg = sarg[c2 * 64 + threadIdx.x]; }
        }
        float acc[13];
#pragma unroll
        for (int o = 0; o < 13; o++) acc[o] = sg.dw[o * (sg.CF + 1)] * mn;
        for (int c = 0; c < sg.CF; c++) {
            float v = sg.feat[(size_t)c * npix + pix];
#pragma unroll
            for (int o = 0; o < 13; o++) acc[o] = fmaf(v, sg.dw[o * (sg.CF + 1) + 1 + c], acc[o]);
        }
        sg.hyp[pix] = (float)arg;
        sg.hyp[npix + pix] = 0.f;
        sg.hyp[2 * (size_t)npix + pix] = 0.f;
#pragma unroll
        for (int o = 0; o < 13; o++) sg.hyp[(size_t)(3 + o) * npix + pix] = lrelu(acc[o] + sg.db[o]);
    }
}

extern "C" void kernel_launch(void* const* d_in, const int* in_sizes, int n_in,
                              void* d_out, int out_size, void* d_ws, size_t ws_size,
                              hipStream_t stream) {
    (void)in_sizes; (void)n_in; (void)out_size; (void)ws_size;
    float* out = (float*)d_out;
    float* ws = (float*)d_ws;

    const int C[5] = {32, 24, 24, 16, 16};
    const int H[5] = {24, 48, 96, 192, 384};
    const int W[5] = {80, 160, 320, 640, 1280};
    const int D[5] = {20, 40, 80, 160, 320};
    const int wa_i[5] = {10, 14, 18, 22, 26};
    const int dw_i[5] = {30, 32, 34, 36, 38};

    const size_t cv_off[5]  = {0, 2400, 21600, 175200, 1404000};
    const size_t hyp_off[5] = {11234400, 11236320, 11244000, 11274720, 11397600};
    const size_t tl_off[5] = {0, 9600, 48000, 201600, 816000};
    const size_t tr_off[5] = {1920, 17280, 78720, 324480, 1307520};
    const size_t wat_off[5] = {3280000, 3288192, 3294336, 3300480, 3304576};
    const size_t wbt_off[5] = {3310000, 3310256, 3310512, 3310768, 3311024};

    const float* fl[5] = {(const float*)d_in[0], (const float*)d_in[1], (const float*)d_in[2],
                          (const float*)d_in[3], (const float*)d_in[4]};
    const float* fr[5] = {(const float*)d_in[5], (const float*)d_in[6], (const float*)d_in[7],
                          (const float*)d_in[8], (const float*)d_in[9]};

    // ---- prep ----
    PrepTab pt;
    for (int l = 0; l < 5; l++) {
        pt.seg[l].wa = (const float*)d_in[wa_i[l]];
        pt.seg[l].wb = (const float*)d_in[wa_i[l] + 2];
        pt.seg[l].wat = ws + wat_off[l];
        pt.seg[l].wbt = ws + wbt_off[l];
        pt.seg[l].CIN = C[l];
    }
    prep_weights<<<5, 256, 0, stream>>>(pt);

    // ---- conv table: biggest segments first ----
    const int ord_lvl[10]  = {4, 4, 3, 3, 2, 2, 1, 1, 0, 0};
    const int ord_side[10] = {1, 0, 1, 0, 1, 0, 1, 0, 1, 0};   // 1 = right
    ConvTab ct;
    int blk = 0;
    for (int i = 0; i < 10; i++) {
        int l = ord_lvl[i]; bool right = ord_side[i];
        ConvSeg& s = ct.seg[i];
        s.in = right ? fr[l] : fl[l];
        s.wat = ws + wat_off[l];
        s.wbt = ws + wbt_off[l];
        s.ba = (const float*)d_in[wa_i[l] + 1];
        s.bb = (const float*)d_in[wa_i[l] + 3];
        s.out = ws + (right ? tr_off[l] : tl_off[l]);
        s.CIN = C[l]; s.H = H[l]; s.W = W[l];
        s.right = right ? 1 : 0;
        int OH = H[l] / 4, W4 = W[l] / 4;
        s.nit = OH * W4;                       // both sides: one work item per 4-col group
        s.npix = right ? OH * W[l] : OH * W4;  // output pixel count
        s.blk0 = blk;
        blk += (s.nit + 255) / 256;
    }
    conv_uber<<<blk, 256, 0, stream>>>(ct);

    // ---- cv table: level 1 (biggest) first ----
    const float* feat[5] = {ws + tl_off[0], ws + tl_off[1], fl[0], fl[1], fl[2]};
    const int   CF[5]    = {16, 16, 32, 24, 24};
    CvTab vt;
    blk = 0;
    for (int i = 0; i < 5; i++) {
        int l = 4 - i;
        CvSeg& s = vt.seg[i];
        s.tl = ws + tl_off[l]; s.tr = ws + tr_off[l];
        s.feat = feat[l];
        s.dw = (const float*)d_in[dw_i[l]];
        s.db = (const float*)d_in[dw_i[l] + 1];
        s.cv = out + cv_off[l]; s.hyp = out + hyp_off[l];
        s.h = H[l] / 4; s.w4 = W[l] / 4; s.w = W[l]; s.D = D[l];
        int ngroups = D[l] / 4;
        s.gpc = (ngroups + 3) / 4;
        s.CF = CF[l];
        s.blk0 = blk;
        blk += (s.h * s.w4 + 63) / 64;
    }
    cv_hyp_uber<<<blk, 256, 0, stream>>>(vt);
}

// Round 6
// 339.668 us; speedup vs baseline: 2.1678x; 2.1678x over previous
//
#include <hip/hip_runtime.h>
#include <float.h>

#define NEG_SLOPE 0.2f

__device__ __forceinline__ float lrelu(float x) { return x >= 0.0f ? x : NEG_SLOPE * x; }

// ============ über tile-conv: 4 px/thread, weights in LDS (broadcast b128 reads) ============
// left (SX=4): 4 outputs/thread, 4 aligned float4 loads per (c,r) (cols 16xg..16xg+15).
// right (SX=1): 4 outputs/thread at 4-aligned column base; 2 aligned float4 loads per (c,r).
// Weights transposed inline during LDS staging: s_wa[c*256 + r*64 + kx*16 + co].
struct ConvSeg {
    const float* in; const float* wa; const float* wb; const float* ba; const float* bb;
    float* out;
    int CIN, H, W, right, nit, npix, blk0;
};
struct ConvTab { ConvSeg seg[10]; };

__global__ __launch_bounds__(256)
void conv_uber(ConvTab tab) {
    __shared__ float s_wa[32 * 256];
    __shared__ float s_wb[256];
    __shared__ float s_ba[16], s_bb[16];

    int si = 0;
#pragma unroll
    for (int i = 1; i < 10; i++) if ((int)blockIdx.x >= tab.seg[i].blk0) si = i;
    const ConvSeg sg = tab.seg[si];
    const int CIN = sg.CIN, W = sg.W, H = sg.H;

    // stage + transpose weights: wa is (16, CIN, 4, 4) -> s_wa[(c,r,kx)][co]
    for (int i = threadIdx.x; i < CIN * 256; i += 256)
        s_wa[i] = sg.wa[(i & 15) * (CIN * 16) + (i >> 4)];
    s_wb[threadIdx.x] = sg.wb[(threadIdx.x & 15) * 16 + (threadIdx.x >> 4)];
    if (threadIdx.x < 16) { s_ba[threadIdx.x] = sg.ba[threadIdx.x]; s_bb[threadIdx.x] = sg.bb[threadIdx.x]; }
    __syncthreads();

    int t = ((int)blockIdx.x - sg.blk0) * 256 + threadIdx.x;
    const bool valid = t < sg.nit;
    int ct = valid ? t : sg.nit - 1;

    float m[4][16];
#pragma unroll
    for (int i = 0; i < 4; i++)
#pragma unroll
        for (int co = 0; co < 16; co++) m[i][co] = 0.f;

    int obase;   // output pixel index of first of the 4 outputs
    if (sg.right) {
        const int W4 = W >> 2;
        int y = ct / W4, xq = ct - y * W4;
        int colb = 4 * xq;
        obase = y * W + colb;
        const float* ib = sg.in + (size_t)(4 * y) * W + colb;
        const bool has1 = colb + 4 < W;
        for (int c = 0; c < CIN; c++) {
            const float* rb = ib + (size_t)c * H * W;
            const float* wc = s_wa + c * 256;
#pragma unroll
            for (int r = 0; r < 4; r++) {
                float4 f0 = *(const float4*)(rb + r * W);
                float4 f1 = make_float4(0.f, 0.f, 0.f, 0.f);
                if (has1) f1 = *(const float4*)(rb + r * W + 4);
                float wv[8] = {f0.x, f0.y, f0.z, f0.w, f1.x, f1.y, f1.z, f1.w};
                const float* wr = wc + r * 64;
#pragma unroll
                for (int kx = 0; kx < 4; kx++) {
                    const float* w2 = wr + kx * 16;   // 16 floats, broadcast ds_read_b128 x4
#pragma unroll
                    for (int i = 0; i < 4; i++) {
                        float v = wv[i + kx];
#pragma unroll
                        for (int co = 0; co < 16; co++) m[i][co] = fmaf(v, w2[co], m[i][co]);
                    }
                }
            }
        }
    } else {
        const int OW4 = W >> 4;          // groups of 4 output px along x
        int y = ct / OW4, xg = ct - y * OW4;
        obase = y * (W >> 2) + 4 * xg;
        const float* ib = sg.in + (size_t)(4 * y) * W + 16 * xg;
        for (int c = 0; c < CIN; c++) {
            const float* rb = ib + (size_t)c * H * W;
            const float* wc = s_wa + c * 256;
#pragma unroll
            for (int r = 0; r < 4; r++) {
                float4 v0 = *(const float4*)(rb + r * W);
                float4 v1 = *(const float4*)(rb + r * W + 4);
                float4 v2 = *(const float4*)(rb + r * W + 8);
                float4 v3 = *(const float4*)(rb + r * W + 12);
                float q[4][4] = {{v0.x, v0.y, v0.z, v0.w}, {v1.x, v1.y, v1.z, v1.w},
                                 {v2.x, v2.y, v2.z, v2.w}, {v3.x, v3.y, v3.z, v3.w}};
                const float* wr = wc + r * 64;
#pragma unroll
                for (int kx = 0; kx < 4; kx++) {
                    const float* w2 = wr + kx * 16;
#pragma unroll
                    for (int i = 0; i < 4; i++) {
                        float v = q[i][kx];
#pragma unroll
                        for (int co = 0; co < 16; co++) m[i][co] = fmaf(v, w2[co], m[i][co]);
                    }
                }
            }
        }
    }

    // epilogue: bias+lrelu, 1x1 conv (LDS broadcast weights), packed float4 stores
    float o[4][16];
#pragma unroll
    for (int i = 0; i < 4; i++) {
#pragma unroll
        for (int co = 0; co < 16; co++) m[i][co] = lrelu(m[i][co] + s_ba[co]);
#pragma unroll
        for (int co = 0; co < 16; co++) o[i][co] = 0.f;
#pragma unroll
        for (int k = 0; k < 16; k++) {
            float mk = m[i][k];
            const float* wr = s_wb + k * 16;
#pragma unroll
            for (int co = 0; co < 16; co++) o[i][co] = fmaf(mk, wr[co], o[i][co]);
        }
    }
    if (valid) {
#pragma unroll
        for (int co = 0; co < 16; co++) {
            float4 v = make_float4(lrelu(o[0][co] + s_bb[co]), lrelu(o[1][co] + s_bb[co]),
                                   lrelu(o[2][co] + s_bb[co]), lrelu(o[3][co] + s_bb[co]));
            *(float4*)(sg.out + (size_t)co * sg.npix + obase) = v;
        }
    }
}

// ============ über cost-volume + argmin + hyp: 16 px x 16 d-chunks per block ============
struct CvSeg {
    const float* tl; const float* tr; const float* feat;
    const float* dw; const float* db;
    float* cv; float* hyp;
    int h, w4, w, D, gpc, CF, blk0;
};
struct CvTab { CvSeg seg[5]; };

__global__ __launch_bounds__(256)
void cv_hyp_uber(CvTab tab) {
    __shared__ float smin[256];
    __shared__ int sarg[256];

    int si = 0;
#pragma unroll
    for (int i = 1; i < 5; i++) if ((int)blockIdx.x >= tab.seg[i].blk0) si = i;
    const CvSeg sg = tab.seg[si];

    const int npix = sg.h * sg.w4;
    const int p = threadIdx.x & 15, chunk = threadIdx.x >> 4;
    const int pix = ((int)blockIdx.x - sg.blk0) * 16 + p;
    const bool valid = pix < npix;

    float mloc = FLT_MAX; int aloc = 0;
    if (valid) {
        int y = pix / sg.w4, j = pix - y * sg.w4;
        float tlv[16]; float sumabs = 0.f;
#pragma unroll
        for (int c = 0; c < 16; c++) { tlv[c] = sg.tl[(size_t)c * npix + pix]; sumabs += fabsf(tlv[c]); }

        int ngroups = sg.D >> 2;
        int g0 = chunk * sg.gpc;
        int g1 = min(ngroups, g0 + sg.gpc);
        const float* trrow = sg.tr + (size_t)y * sg.w;
        int hw = sg.h * sg.w;

        float carry[16];
        int b0 = 4 * j - 4 * g0;
        if (g0 < g1 && b0 >= 0) {
#pragma unroll
            for (int c = 0; c < 16; c++) carry[c] = trrow[(size_t)c * hw + b0];
        }
        for (int g = g0; g < g1; g++) {
            int b = 4 * j - 4 * g;
            float a0, a1, a2, a3;
            if (b >= 4) {
                a0 = a1 = a2 = a3 = 0.f;
#pragma unroll
                for (int c = 0; c < 16; c++) {
                    float4 f0 = *(const float4*)(trrow + (size_t)c * hw + (b - 4));
                    float tv = tlv[c];
                    a0 += fabsf(tv - carry[c]);
                    a1 += fabsf(tv - f0.w);
                    a2 += fabsf(tv - f0.z);
                    a3 += fabsf(tv - f0.y);
                    carry[c] = f0.x;
                }
            } else if (b == 0) {
                a0 = 0.f; a1 = a2 = a3 = sumabs;
#pragma unroll
                for (int c = 0; c < 16; c++) a0 += fabsf(tlv[c] - carry[c]);
            } else {
                a0 = a1 = a2 = a3 = sumabs;
            }
            float* cvp = sg.cv + (size_t)(4 * g) * npix + pix;
            cvp[0] = a0; cvp[npix] = a1; cvp[2 * (size_t)npix] = a2; cvp[3 * (size_t)npix] = a3;
            if (a0 < mloc) { mloc = a0; aloc = 4 * g; }
            if (a1 < mloc) { mloc = a1; aloc = 4 * g + 1; }
            if (a2 < mloc) { mloc = a2; aloc = 4 * g + 2; }
            if (a3 < mloc) { mloc = a3; aloc = 4 * g + 3; }
        }
    }
    smin[threadIdx.x] = mloc;
    sarg[threadIdx.x] = aloc;
    __syncthreads();

    if (threadIdx.x < 16 && valid) {
        float mn = smin[threadIdx.x]; int arg = sarg[threadIdx.x];
#pragma unroll
        for (int c2 = 1; c2 < 16; c2++) {    // ascending chunk = ascending d; strict <
            float v = smin[c2 * 16 + threadIdx.x];
            if (v < mn) { mn = v; arg = sarg[c2 * 16 + threadIdx.x]; }
        }
        float acc[13];
#pragma unroll
        for (int o = 0; o < 13; o++) acc[o] = sg.dw[o * (sg.CF + 1)] * mn;
        for (int c = 0; c < sg.CF; c++) {
            float v = sg.feat[(size_t)c * npix + pix];
#pragma unroll
            for (int o = 0; o < 13; o++) acc[o] = fmaf(v, sg.dw[o * (sg.CF + 1) + 1 + c], acc[o]);
        }
        sg.hyp[pix] = (float)arg;
        sg.hyp[npix + pix] = 0.f;
        sg.hyp[2 * (size_t)npix + pix] = 0.f;
#pragma unroll
        for (int o = 0; o < 13; o++) sg.hyp[(size_t)(3 + o) * npix + pix] = lrelu(acc[o] + sg.db[o]);
    }
}

extern "C" void kernel_launch(void* const* d_in, const int* in_sizes, int n_in,
                              void* d_out, int out_size, void* d_ws, size_t ws_size,
                              hipStream_t stream) {
    (void)in_sizes; (void)n_in; (void)out_size; (void)ws_size;
    float* out = (float*)d_out;
    float* ws = (float*)d_ws;

    const int C[5] = {32, 24, 24, 16, 16};
    const int H[5] = {24, 48, 96, 192, 384};
    const int W[5] = {80, 160, 320, 640, 1280};
    const int D[5] = {20, 40, 80, 160, 320};
    const int wa_i[5] = {10, 14, 18, 22, 26};
    const int dw_i[5] = {30, 32, 34, 36, 38};

    const size_t cv_off[5]  = {0, 2400, 21600, 175200, 1404000};
    const size_t hyp_off[5] = {11234400, 11236320, 11244000, 11274720, 11397600};
    const size_t tl_off[5] = {0, 9600, 48000, 201600, 816000};
    const size_t tr_off[5] = {1920, 17280, 78720, 324480, 1307520};

    const float* fl[5] = {(const float*)d_in[0], (const float*)d_in[1], (const float*)d_in[2],
                          (const float*)d_in[3], (const float*)d_in[4]};
    const float* fr[5] = {(const float*)d_in[5], (const float*)d_in[6], (const float*)d_in[7],
                          (const float*)d_in[8], (const float*)d_in[9]};

    // ---- conv table: biggest segments first ----
    const int ord_lvl[10]  = {4, 4, 3, 3, 2, 2, 1, 1, 0, 0};
    const int ord_side[10] = {1, 0, 1, 0, 1, 0, 1, 0, 1, 0};   // 1 = right
    ConvTab ct;
    int blk = 0;
    for (int i = 0; i < 10; i++) {
        int l = ord_lvl[i]; bool right = ord_side[i];
        ConvSeg& s = ct.seg[i];
        s.in = right ? fr[l] : fl[l];
        s.wa = (const float*)d_in[wa_i[l]];
        s.ba = (const float*)d_in[wa_i[l] + 1];
        s.wb = (const float*)d_in[wa_i[l] + 2];
        s.bb = (const float*)d_in[wa_i[l] + 3];
        s.out = ws + (right ? tr_off[l] : tl_off[l]);
        s.CIN = C[l]; s.H = H[l]; s.W = W[l];
        s.right = right ? 1 : 0;
        int OH = H[l] / 4, W4 = W[l] / 4;
        s.nit = right ? OH * W4 : OH * (W4 / 4);   // 4 outputs per work item
        s.npix = right ? OH * W[l] : OH * W4;
        s.blk0 = blk;
        blk += (s.nit + 255) / 256;
    }
    conv_uber<<<blk, 256, 0, stream>>>(ct);

    // ---- cv table: level 1 (biggest) first; 16 px x 16 d-chunks per block ----
    const float* feat[5] = {ws + tl_off[0], ws + tl_off[1], fl[0], fl[1], fl[2]};
    const int   CF[5]    = {16, 16, 32, 24, 24};
    CvTab vt;
    blk = 0;
    for (int i = 0; i < 5; i++) {
        int l = 4 - i;
        CvSeg& s = vt.seg[i];
        s.tl = ws + tl_off[l]; s.tr = ws + tr_off[l];
        s.feat = feat[l];
        s.dw = (const float*)d_in[dw_i[l]];
        s.db = (const float*)d_in[dw_i[l] + 1];
        s.cv = out + cv_off[l]; s.hyp = out + hyp_off[l];
        s.h = H[l] / 4; s.w4 = W[l] / 4; s.w = W[l]; s.D = D[l];
        int ngroups = D[l] / 4;
        s.gpc = (ngroups + 15) / 16;
        s.CF = CF[l];
        s.blk0 = blk;
        blk += (s.h * s.w4 + 15) / 16;
    }
    cv_hyp_uber<<<blk, 256, 0, stream>>>(vt);
}